// Round 4
// baseline (636.154 us; speedup 1.0000x reference)
//
#include <hip/hip_runtime.h>

// Problem constants (fixed shapes from setup_inputs)
#define B 8
#define I 32
#define O 32
#define D 8
#define H 14
#define W 14
#define K 9
#define WK (W*K)              // 126
#define DSTRIDE (H*W*K)       // 1764
#define OSTRIDE (D*H*W*K)     // 14112
#define ISTRIDE (O*D*H*W*K)   // 451584
#define BSTRIDE ((size_t)I*ISTRIDE)
#define SUBSET 26             // ceil(0.8 * 32)

// One block per (b, o, h); 448 threads. Thread remap vs scalar version:
//   t = i*14 + wp*2 + dh   ->  thread covers w in {2wp, 2wp+1} and d in [4dh, 4dh+4)
// so each thread loads 4 d-rows x 18 CONTIGUOUS floats starting at an EVEN float
// offset (w0*9, w0 even) => 36 x global_load_dwordx2 (8B/lane), replacing the old
// 72 scalar dword loads. Cross-d-half reductions (per-k norms, |y|, loss) combine
// with one __shfl_xor(.,1) to the adjacent lane (same i, same w-pair, other d-half).
// Per-(i,w) phases (rank/threshold) have exactly one owner thread: wm = 2wp+dh.
__global__ __launch_bounds__(448) void caps_route_kernel(const float* __restrict__ x,
                                                         float* __restrict__ out) {
    const int bid = blockIdx.x;
    const int h = bid % H;
    const int o = (bid / H) % O;
    const int b = bid / (H * O);
    const int t = threadIdx.x;

    const int i  = t / W;            // 0..31
    const int r  = t - i * W;        // 0..13
    const int wp = r >> 1;           // 0..6
    const int dh = r & 1;            // 0,1  (low bit of t: i*14 and wp*2 are even)
    const int w0 = wp << 1;          // even w of the pair
    const int wm = w0 + dh;          // the (i,w) this thread owns in LDS phases
    const int d0 = dh << 2;          // 0 or 4

    __shared__ float ys[I][D][W];    // K-reduced capsules
    __shared__ float ns_s[I][W];     // norm over D of ys
    __shared__ float ls_s[I][W];     // losses
    __shared__ float vsh[D][W];      // consensus
    __shared__ float thr_s[W];       // kth-smallest loss per pixel

    const float* xp = x + (size_t)b * BSTRIDE + (size_t)i * ISTRIDE
                        + (size_t)o * OSTRIDE + (size_t)d0 * DSTRIDE
                        + (size_t)h * WK + (size_t)w0 * K;

    // ---- vectorized load: 4 d-rows x 18 contiguous floats = 9 float2 each ----
    float xv[4][18];
    #pragma unroll
    for (int dd = 0; dd < 4; ++dd) {
        const float2* p2 = reinterpret_cast<const float2*>(xp + dd * DSTRIDE);
        #pragma unroll
        for (int e = 0; e < 9; ++e) {
            float2 v = p2[e];
            xv[dd][2*e]   = v.x;
            xv[dd][2*e+1] = v.y;
        }
    }

    // ---- per-k sum of squares over this thread's 4 d's (both pixels),
    //      pair-combine with the other d-half via shfl_xor(1) ----
    float nk[2][K];
    float den[2];
    #pragma unroll
    for (int ww = 0; ww < 2; ++ww) {
        den[ww] = 0.f;
        #pragma unroll
        for (int k = 0; k < K; ++k) {
            float s = 0.f;
            #pragma unroll
            for (int dd = 0; dd < 4; ++dd) {
                float v = xv[dd][ww * K + k];
                s += v * v;
            }
            s += __shfl_xor(s, 1);     // add the partner's 4 d's
            float n = sqrtf(s);
            nk[ww][k] = n;
            den[ww] += n;
        }
    }
    const float invden0 = 1.f / den[0];
    const float invden1 = 1.f / den[1];

    // ---- K-weighted average y; store adjacent w's as one 8B LDS write ----
    float y[4][2];
    float s2p0 = 0.f, s2p1 = 0.f;
    #pragma unroll
    for (int dd = 0; dd < 4; ++dd) {
        float num0 = 0.f, num1 = 0.f;
        #pragma unroll
        for (int k = 0; k < K; ++k) {
            num0 += nk[0][k] * xv[dd][k];
            num1 += nk[1][k] * xv[dd][K + k];
        }
        const float y0 = num0 * invden0;
        const float y1 = num1 * invden1;
        y[dd][0] = y0;
        y[dd][1] = y1;
        s2p0 += y0 * y0;
        s2p1 += y1 * y1;
        *reinterpret_cast<float2*>(&ys[i][d0 + dd][w0]) = make_float2(y0, y1);
    }
    // norm over all 8 d (compile-time-indexed shfls: both lanes pass same slot)
    const float s2t0 = s2p0 + __shfl_xor(s2p0, 1);
    const float s2t1 = s2p1 + __shfl_xor(s2p1, 1);
    ns_s[i][wm] = sqrtf(dh ? s2t1 : s2t0);
    __syncthreads();

    // ---- consensus v[d][w] (112 threads) ----
    if (t < D * W) {
        const int d = t / W, w2 = t - (t / W) * W;
        float num = 0.f, dn = 0.f;
        #pragma unroll
        for (int j = 0; j < I; ++j) {
            float nv = ns_s[j][w2];
            num += nv * ys[j][d][w2];
            dn += nv;
        }
        vsh[d][w2] = num / dn;
    }
    __syncthreads();

    // ---- losses: partial over this thread's 4 d, pair-combine ----
    float lp0 = 0.f, lp1 = 0.f;
    #pragma unroll
    for (int dd = 0; dd < 4; ++dd) {
        lp0 += vsh[d0 + dd][w0]     * y[dd][0];
        lp1 += vsh[d0 + dd][w0 + 1] * y[dd][1];
    }
    const float l0 = lp0 + __shfl_xor(lp0, 1);
    const float l1 = lp1 + __shfl_xor(lp1, 1);
    const float lv = -(dh ? l1 : l0);
    ls_s[i][wm] = lv;
    __syncthreads();

    // ---- kth smallest (stable rank) for the owned (i, wm) ----
    int rank = 0;
    #pragma unroll
    for (int j = 0; j < I; ++j) {
        float lj = ls_s[j][wm];
        rank += (lj < lv || (lj == lv && j < i)) ? 1 : 0;
    }
    if (rank == SUBSET - 1) thr_s[wm] = lv;
    __syncthreads();

    // ---- masked weighted average -> out[b][o][d][h][w] (112 threads) ----
    if (t < D * W) {
        const int d = t / W, w2 = t - (t / W) * W;
        const float tw = thr_s[w2];
        float num = 0.f, dn = 0.f;
        #pragma unroll
        for (int j = 0; j < I; ++j) {
            float m  = (ls_s[j][w2] <= tw) ? 1.f : 0.f;
            float nv = m * ns_s[j][w2];
            num += nv * ys[j][d][w2];
            dn  += nv;
        }
        out[(((size_t)b * O + o) * D + d) * (H * W) + h * W + w2] = num / dn;
    }
}

extern "C" void kernel_launch(void* const* d_in, const int* in_sizes, int n_in,
                              void* d_out, int out_size, void* d_ws, size_t ws_size,
                              hipStream_t stream) {
    const float* x = (const float*)d_in[0];
    float* out = (float*)d_out;
    dim3 grid(B * O * H);   // 3584 blocks
    dim3 block(I * W);      // 448 threads = 7 waves
    caps_route_kernel<<<grid, block, 0, stream>>>(x, out);
}

// Round 5
// 606.908 us; speedup vs baseline: 1.0482x; 1.0482x over previous
//
#include <hip/hip_runtime.h>

// Problem constants (fixed shapes from setup_inputs)
#define B 8
#define I 32
#define O 32
#define D 8
#define H 14
#define W 14
#define K 9
#define WK (W*K)              // 126
#define DSTRIDE (H*W*K)       // 1764
#define OSTRIDE (D*H*W*K)     // 14112
#define ISTRIDE (O*D*H*W*K)   // 451584
#define BSTRIDE ((size_t)I*ISTRIDE)
#define SUBSET 26             // ceil(0.8 * 32)

// One block per (b, o, h); 448 threads = one per (i, w) pair.
// Each thread loads its 72 floats x[b,i,o,0:8,h,w,0:9] into registers (all
// independent -> deep MLP, no barriers during load), computes per-k norms,
// K-weighted average ys[i][:][w] and its norm ns in registers, then 4 short
// LDS phases: consensus v, losses, kth-smallest threshold (stable rank),
// masked weighted average.
//
// NOTE (round-4 post-mortem): the measurement window is combined-HBM-traffic
// bound (~4.16 GB: 3.7 GB harness poison fills + 462 MB kernel input read,
// overlapped, at ~6.9 TB/s). A float2-vectorized load variant measured 636 us
// vs this version's 607 us — VMEM instruction count is irrelevant here and the
// pair-split access pattern lowered DRAM efficiency. Keep the scalar layout.
__global__ __launch_bounds__(448) void caps_route_kernel(const float* __restrict__ x,
                                                         float* __restrict__ out) {
    const int bid = blockIdx.x;
    const int h = bid % H;
    const int o = (bid / H) % O;
    const int b = bid / (H * O);
    const int t = threadIdx.x;
    const int i = t / W;      // 0..31
    const int w = t - i * W;  // 0..13

    __shared__ float ys[I][D][W];   // K-reduced capsules
    __shared__ float ns_s[I][W];    // norm over D of ys
    __shared__ float ls_s[I][W];    // losses
    __shared__ float vsh[D][W];     // consensus
    __shared__ float thr_s[W];      // kth-smallest loss per pixel

    const float* xp = x + (size_t)b * BSTRIDE + (size_t)i * ISTRIDE
                        + (size_t)o * OSTRIDE + (size_t)h * WK + (size_t)w * K;

    // ---- load 72 floats into registers (all loads independent) ----
    float xv[D][K];
    #pragma unroll
    for (int d = 0; d < D; ++d) {
        #pragma unroll
        for (int k = 0; k < K; ++k) {
            xv[d][k] = xp[d * DSTRIDE + k];
        }
    }

    // ---- per-k norm over D, then K-weighted average -> y[d], ns ----
    float nk[K];
    float den = 0.f;
    #pragma unroll
    for (int k = 0; k < K; ++k) {
        float s = 0.f;
        #pragma unroll
        for (int d = 0; d < D; ++d) { float v = xv[d][k]; s += v * v; }
        nk[k] = sqrtf(s);
        den += nk[k];
    }
    const float inv_den = 1.f / den;

    float y[D];
    float s2 = 0.f;
    #pragma unroll
    for (int d = 0; d < D; ++d) {
        float num = 0.f;
        #pragma unroll
        for (int k = 0; k < K; ++k) num += nk[k] * xv[d][k];
        y[d] = num * inv_den;
        ys[i][d][w] = y[d];
        s2 += y[d] * y[d];
    }
    const float nsv = sqrtf(s2);
    ns_s[i][w] = nsv;
    __syncthreads();

    // ---- consensus v[d][w] (112 threads) ----
    if (t < D * W) {
        const int d = t / W, w2 = t - (t / W) * W;
        float num = 0.f, dn = 0.f;
        #pragma unroll
        for (int j = 0; j < I; ++j) {
            float nv = ns_s[j][w2];
            num += nv * ys[j][d][w2];
            dn += nv;
        }
        vsh[d][w2] = num / dn;
    }
    __syncthreads();

    // ---- losses[i][w] = -sum_d v[d][w]*y[d] (all 448 threads, y in regs) ----
    float lv = 0.f;
    #pragma unroll
    for (int d = 0; d < D; ++d) lv += vsh[d][w] * y[d];
    lv = -lv;
    ls_s[i][w] = lv;
    __syncthreads();

    // ---- kth smallest (k=SUBSET) via stable rank; matches jnp.sort[...,25] ----
    int rank = 0;
    #pragma unroll
    for (int j = 0; j < I; ++j) {
        float lj = ls_s[j][w];
        rank += (lj < lv || (lj == lv && j < i)) ? 1 : 0;
    }
    if (rank == SUBSET - 1) thr_s[w] = lv;
    __syncthreads();

    // ---- masked weighted average -> out[b][o][d][h][w] (112 threads) ----
    if (t < D * W) {
        const int d = t / W, w2 = t - (t / W) * W;
        const float tw = thr_s[w2];
        float num = 0.f, dn = 0.f;
        #pragma unroll
        for (int j = 0; j < I; ++j) {
            float m  = (ls_s[j][w2] <= tw) ? 1.f : 0.f;
            float nv = m * ns_s[j][w2];
            num += nv * ys[j][d][w2];
            dn  += nv;
        }
        out[(((size_t)b * O + o) * D + d) * (H * W) + h * W + w2] = num / dn;
    }
}

extern "C" void kernel_launch(void* const* d_in, const int* in_sizes, int n_in,
                              void* d_out, int out_size, void* d_ws, size_t ws_size,
                              hipStream_t stream) {
    const float* x = (const float*)d_in[0];
    float* out = (float*)d_out;
    dim3 grid(B * O * H);   // 3584 blocks
    dim3 block(I * W);      // 448 threads = 7 waves
    caps_route_kernel<<<grid, block, 0, stream>>>(x, out);
}